// Round 6
// baseline (3717.183 us; speedup 1.0000x reference)
//
#include <hip/hip_runtime.h>

// ============================================================================
// Hyper_GRU pipeline on MI355X (gfx950), round 5.
// Fix vs round 4 attempt: gru_k x-staging covered only 128/256 elems per row
// after the 512->256 thread change (xo=(tid&15)*8) -> upper half of sX was
// 0xAA poison -> NaN. Now each of 16 threads/seq stages 16 elems.
// gru_k design (unchanged): 4 waves, 1 wave/SIMD, 512-VGPR cap; Whh register-
// resident (384 VGPR), Wih streamed from L2; r/z share accumulators; gate
// math in MFMA C-layout registers; biases in LDS.
// ============================================================================

typedef float f32x4 __attribute__((ext_vector_type(4)));
typedef _Float16 half8 __attribute__((ext_vector_type(8)));

#define NGRAPH 512

// ---- workspace arena (bytes); peak 109,051,904 ------------------------------
#define O_SA 0L
#define O_SP 2048L
#define O_SH 4096L
#define O_WH 8192L             // f16 weights: 1,310,720 elems -> ends 2,629,632
#define O_H0 2629632L          // 512*256 f32 -> 3,153,920
#define O_Q1 4194304L          // 10,485,760 -> 14,680,064   (=A1 in-place)
#define O_K1 14680064L         // 20,971,520 -> 35,651,584
#define O_V1 35651584L         // 20,971,520 -> 56,623,104
#define O_Q2 4194304L          // 52,428,800 -> 56,623,104  aliases Q1+K1+V1 (dead)
#define O_P2 56623104L         // 10,485,760 -> 67,108,864
#define O_K2 67108864L         // 10,485,760 -> 77,594,624
#define O_V2 77594624L         // 10,485,760 -> 88,080,384
#define O_H16 56623104L        // 52,428,800 -> 109,051,904 aliases P2,K2,V2 (dead)

// weight element offsets inside WH arena
#define W_P2H_WQ 0
#define W_P2H_WK 65536
#define W_P2H_WV 131072
#define W_P2H_WO 196608
#define W_A2P_WQ 262144
#define W_A2P_WK 327680
#define W_A2P_WV 393216
#define W_A2P_WO 458752
#define W_WIH_F 524288
#define W_WHH_F 720896
#define W_WIH_B 917504
#define W_WHH_B 1114112

// ============================================================================
// small kernels
// ============================================================================

__global__ void prefix_k(const int* __restrict__ ca, const int* __restrict__ cp,
                         const int* __restrict__ chh,
                         int* __restrict__ sa, int* __restrict__ sp, int* __restrict__ sh) {
  __shared__ int buf[512];
  int tid = threadIdx.x;
  for (int m = 0; m < 3; ++m) {
    const int* src = (m == 0) ? ca : (m == 1) ? cp : chh;
    int* dst = (m == 0) ? sa : (m == 1) ? sp : sh;
    int v = src[tid];
    buf[tid] = v;
    __syncthreads();
    for (int off = 1; off < 512; off <<= 1) {
      int add = (tid >= off) ? buf[tid - off] : 0;
      __syncthreads();
      buf[tid] += add;
      __syncthreads();
    }
    dst[tid] = buf[tid] - v;   // exclusive
    __syncthreads();
  }
}

__global__ void wconv_k(const float* s0, const float* s1, const float* s2, const float* s3,
                        const float* s4, const float* s5, const float* s6, const float* s7,
                        const float* s8, const float* s9, const float* s10, const float* s11,
                        _Float16* __restrict__ dst) {
  long i = (long)blockIdx.x * 256 + threadIdx.x;   // grid covers exactly 1,310,720
  const float* s;
  long off;
  if (i < 524288) {
    int m = (int)(i >> 16);
    off = i & 65535;
    s = (m == 0) ? s0 : (m == 1) ? s1 : (m == 2) ? s2 : (m == 3) ? s3
      : (m == 4) ? s4 : (m == 5) ? s5 : (m == 6) ? s6 : s7;
  } else {
    long r = i - 524288;
    int m = (int)(r / 196608);
    off = r - (long)m * 196608;
    s = (m == 0) ? s8 : (m == 1) ? s9 : (m == 2) ? s10 : s11;
  }
  dst[i] = (_Float16)s[off];
}

// h0[b][j] = max_t h[b][t][j]  (all 200 rows incl. padded — matches ref)
__global__ void maxpool_k(const _Float16* __restrict__ h, float* __restrict__ h0) {
  int b = blockIdx.x, j = threadIdx.x;
  float m = -1e30f;
  for (int t = 0; t < 200; ++t) m = fmaxf(m, (float)h[((long)b * 200 + t) * 256 + j]);
  h0[b * 256 + j] = m;
}

// ============================================================================
// GEMM: C[M,N] = A[M,256] @ W[N,256]^T (+bias) (+gathered residual), f16 out.
// GF_GATHER: A rows come from ragged f32 msg (pad/convert fused into staging).
// 128x128 tile, BK=32, 4 waves (2x2), 4x4 16x16x32 MFMAs per wave. M,N %128==0.
// ============================================================================
#define GF_BIAS 1
#define GF_RES  2
#define GF_GATHER 4

template <int FLAGS>
__global__ __launch_bounds__(256, 2)
void gemm_bt(const _Float16* __restrict__ A, const _Float16* __restrict__ W,
             const float* __restrict__ bias, _Float16* __restrict__ Ch,
             const float* __restrict__ rmsg, const int* __restrict__ rcnt,
             const int* __restrict__ rstart, int rmaxn, int N) {
  __shared__ _Float16 sA[128 * 40];   // rows padded 32->40
  __shared__ _Float16 sB[128 * 40];
  const int tid = threadIdx.x;
  const int lane = tid & 63, wave = tid >> 6;
  const int wr = wave >> 1, wc = wave & 1;
  const long bm0 = (long)blockIdx.y * 128;
  const long bn0 = (long)blockIdx.x * 128;
  const int r0 = tid >> 2, c0 = tid & 3;            // thread stages rows r0, r0+64
  const _Float16* gB = W + (bn0 + r0) * 256 + c0 * 8;

  const _Float16* gA0 = nullptr;
  const _Float16* gA1 = nullptr;
  const float* gs0 = nullptr;
  const float* gs1 = nullptr;
  bool v0 = false, v1 = false;
  if (FLAGS & GF_GATHER) {
    int row0 = (int)bm0 + r0, row1 = row0 + 64;
    int b0 = row0 / rmaxn, p0 = row0 - b0 * rmaxn;
    int b1 = row1 / rmaxn, p1 = row1 - b1 * rmaxn;
    v0 = p0 < rcnt[b0];
    v1 = p1 < rcnt[b1];
    gs0 = rmsg + (long)(rstart[b0] + p0) * 256 + c0 * 8;
    gs1 = rmsg + (long)(rstart[b1] + p1) * 256 + c0 * 8;
  } else {
    gA0 = A + (bm0 + r0) * 256 + c0 * 8;
    gA1 = gA0 + 64 * 256;
  }
  auto loadA = [&](int kt, bool hi) -> half8 {
    if (FLAGS & GF_GATHER) {
      half8 h = {};
      const float* g = hi ? gs1 : gs0;
      if (hi ? v1 : v0) {
        float4 f0 = *(const float4*)(g + kt * 32);
        float4 f1 = *(const float4*)(g + kt * 32 + 4);
        h[0] = (_Float16)f0.x; h[1] = (_Float16)f0.y;
        h[2] = (_Float16)f0.z; h[3] = (_Float16)f0.w;
        h[4] = (_Float16)f1.x; h[5] = (_Float16)f1.y;
        h[6] = (_Float16)f1.z; h[7] = (_Float16)f1.w;
      }
      return h;
    } else {
      return hi ? *(const half8*)(gA1 + kt * 32) : *(const half8*)(gA0 + kt * 32);
    }
  };

  f32x4 acc[4][4] = {};
  half8 ra0 = loadA(0, false);
  half8 ra1 = loadA(0, true);
  half8 rb0 = *(const half8*)(gB);
  half8 rb1 = *(const half8*)(gB + 64 * 256);
  const int ar = lane & 15, kq = (lane >> 4) * 8;
  for (int kt = 0; kt < 8; ++kt) {
    __syncthreads();
    *(half8*)(sA + r0 * 40 + c0 * 8) = ra0;
    *(half8*)(sA + (r0 + 64) * 40 + c0 * 8) = ra1;
    *(half8*)(sB + r0 * 40 + c0 * 8) = rb0;
    *(half8*)(sB + (r0 + 64) * 40 + c0 * 8) = rb1;
    __syncthreads();
    if (kt < 7) {
      ra0 = loadA(kt + 1, false);
      ra1 = loadA(kt + 1, true);
      rb0 = *(const half8*)(gB + (kt + 1) * 32);
      rb1 = *(const half8*)(gB + 64 * 256 + (kt + 1) * 32);
    }
    half8 af[4], bf[4];
#pragma unroll
    for (int mt = 0; mt < 4; ++mt)
      af[mt] = *(const half8*)(sA + (wr * 64 + mt * 16 + ar) * 40 + kq);
#pragma unroll
    for (int nt = 0; nt < 4; ++nt)
      bf[nt] = *(const half8*)(sB + (wc * 64 + nt * 16 + ar) * 40 + kq);
#pragma unroll
    for (int mt = 0; mt < 4; ++mt)
#pragma unroll
      for (int nt = 0; nt < 4; ++nt)
        acc[mt][nt] = __builtin_amdgcn_mfma_f32_16x16x32_f16(af[mt], bf[nt], acc[mt][nt], 0, 0, 0);
  }
  // epilogue: C/D layout col=lane&15, row=(lane>>4)*4+reg (m89-verified)
  const int cr = (lane >> 4) * 4, cc = lane & 15;
#pragma unroll
  for (int mt = 0; mt < 4; ++mt) {
#pragma unroll
    for (int nt = 0; nt < 4; ++nt) {
      const long col = bn0 + wc * 64 + nt * 16 + cc;
      float bv = (FLAGS & GF_BIAS) ? bias[col] : 0.f;
#pragma unroll
      for (int r = 0; r < 4; ++r) {
        const long row = bm0 + wr * 64 + mt * 16 + cr + r;
        float v = acc[mt][nt][r] + bv;
        if (FLAGS & GF_RES) {     // residual = re-gathered ragged message (f32)
          int bb = (int)(row / rmaxn);
          int p = (int)(row - (long)bb * rmaxn);
          if (p < rcnt[bb]) v += rmsg[(long)(rstart[bb] + p) * 256 + col];
        }
        Ch[row * N + col] = (_Float16)v;
      }
    }
  }
}

// ============================================================================
// Fused MHA per (head, graph): S = Q K^T/8, masked softmax (uniform over all
// MAXK keys when the query row is padded — matches ref's -1e9 fill), O = P V.
// Og may alias Qg (in-place): block (h,b) touches only its own (b, 64-col
// slice); within a block, chunk-c reads precede chunk-c writes (barriered).
// ============================================================================
template <int MAXQ, int MAXK, int NKP, int KKP, int CH, int SSTR, int VSTR>
__global__ __launch_bounds__(256, 2)
void mha_k(const _Float16* Qg, const _Float16* __restrict__ Kg,
           const _Float16* __restrict__ Vg, _Float16* Og,
           const int* __restrict__ qcnt, const int* __restrict__ kcnt) {
  constexpr int MTOT = (MAXQ + 15) & ~15;
  constexpr int NCH = (MTOT + CH - 1) / CH;
  __shared__ float sS[CH * SSTR];
  __shared__ _Float16 sK[NKP * 72];
  __shared__ _Float16 sV[64 * VSTR];   // V transposed: sV[d][kk]
  const int h = blockIdx.x, b = blockIdx.y;
  const int tid = threadIdx.x, lane = tid & 63, wave = tid >> 6;
  const int qc = qcnt[b], kc = kcnt[b];
  const long qbase = ((long)b * MAXQ) * 256 + h * 64;
  const long kbase = ((long)b * MAXK) * 256 + h * 64;
  const int ar = lane & 15, kq = (lane >> 4) * 8;
  for (int i = tid; i < NKP * 64; i += 256) {
    int k = i >> 6, d = i & 63;
    sK[k * 72 + d] = (k < MAXK) ? Kg[kbase + (long)k * 256 + d] : (_Float16)0.f;
  }
  for (int i = tid; i < KKP * 64; i += 256) {
    int kk = i >> 6, d = i & 63;
    sV[d * VSTR + kk] = (kk < MAXK) ? Vg[kbase + (long)kk * 256 + d] : (_Float16)0.f;
  }
  __syncthreads();
  for (int ch = 0; ch < NCH; ++ch) {
    const int rows = (CH < MTOT - ch * CH) ? CH : (MTOT - ch * CH);
    const int mt_n = rows >> 4, st_n = NKP >> 4;
    // ---- scores ----
    for (int idx = wave; idx < mt_n * st_n; idx += 4) {
      int lmt = idx / st_n, nt = idx - lmt * st_n;
      int q = ch * CH + lmt * 16 + ar;
      int n0 = nt * 16;
      f32x4 acc = {0.f, 0.f, 0.f, 0.f};
#pragma unroll
      for (int ks = 0; ks < 2; ++ks) {
        half8 a = {};
        if (q < MAXQ) a = *(const half8*)(Qg + qbase + (long)q * 256 + ks * 32 + kq);
        half8 bb = *(const half8*)(sK + (n0 + ar) * 72 + ks * 32 + kq);
        acc = __builtin_amdgcn_mfma_f32_16x16x32_f16(a, bb, acc, 0, 0, 0);
      }
      int sr = lmt * 16 + (lane >> 4) * 4, sc = n0 + ar;
#pragma unroll
      for (int r = 0; r < 4; ++r) sS[(sr + r) * SSTR + sc] = acc[r];
    }
    __syncthreads();
    // ---- softmax per row ----
    if (tid < rows) {
      int q = ch * CH + tid;
      float sv[MAXK];
#pragma unroll
      for (int k4 = 0; k4 < MAXK / 4; ++k4) {
        f32x4 v = *(const f32x4*)&sS[tid * SSTR + k4 * 4];
        sv[k4 * 4 + 0] = v[0]; sv[k4 * 4 + 1] = v[1];
        sv[k4 * 4 + 2] = v[2]; sv[k4 * 4 + 3] = v[3];
      }
      if (q < qc) {
        float m = -1e30f;
#pragma unroll
        for (int k = 0; k < MAXK; ++k) if (k < kc) m = fmaxf(m, sv[k]);
        float s = 0.f;
#pragma unroll
        for (int k = 0; k < MAXK; ++k) {
          float e = (k < kc) ? __expf((sv[k] - m) * 0.125f) : 0.f;
          sv[k] = e; s += e;
        }
        float inv = 1.f / s;
#pragma unroll
        for (int k = 0; k < MAXK; ++k) sv[k] *= inv;
      } else {
#pragma unroll
        for (int k = 0; k < MAXK; ++k) sv[k] = 1.f / (float)MAXK;
      }
#pragma unroll
      for (int k4 = 0; k4 < MAXK / 4; ++k4) {
        f32x4 v; v[0] = sv[k4*4+0]; v[1] = sv[k4*4+1]; v[2] = sv[k4*4+2]; v[3] = sv[k4*4+3];
        *(f32x4*)&sS[tid * SSTR + k4 * 4] = v;
      }
      for (int k = MAXK; k < KKP; ++k) sS[tid * SSTR + k] = 0.f;
    }
    __syncthreads();
    // ---- P @ V ----
    for (int idx = wave; idx < mt_n * 4; idx += 4) {
      int lmt = idx >> 2, nt = idx & 3;
      int lm = lmt * 16 + ar;
      f32x4 acc = {0.f, 0.f, 0.f, 0.f};
#pragma unroll
      for (int ks = 0; ks < KKP / 32; ++ks) {
        const float* ps = &sS[lm * SSTR + ks * 32 + kq];
        f32x4 p0 = *(const f32x4*)ps;
        f32x4 p1 = *(const f32x4*)(ps + 4);
        half8 a;
        a[0] = (_Float16)p0[0]; a[1] = (_Float16)p0[1]; a[2] = (_Float16)p0[2]; a[3] = (_Float16)p0[3];
        a[4] = (_Float16)p1[0]; a[5] = (_Float16)p1[1]; a[6] = (_Float16)p1[2]; a[7] = (_Float16)p1[3];
        half8 bb = *(const half8*)(sV + (nt * 16 + ar) * VSTR + ks * 32 + kq);
        acc = __builtin_amdgcn_mfma_f32_16x16x32_f16(a, bb, acc, 0, 0, 0);
      }
      int q0 = ch * CH + lmt * 16 + (lane >> 4) * 4;
      int dcol = nt * 16 + ar;
#pragma unroll
      for (int r = 0; r < 4; ++r) {
        int q = q0 + r;
        if (q < MAXQ) Og[qbase + (long)q * 256 + dcol] = (_Float16)acc[r];
      }
    }
    __syncthreads();
  }
}

// ============================================================================
// GRU recurrence, fwd+bwd. 64 blocks x 256 threads (4 waves, 1 wave/SIMD,
// VGPR cap 512). Block owns 16 seqs of one direction. Wave w owns gate dims
// [64w,64w+64) of all three gates. Whh REGISTER-RESIDENT: 12 ntiles x 8
// kfrags = 96 half8 = 384 VGPR, loaded once before the loop. Wih streamed
// from L2 each step (non-recurrent operand). r/z share accumulators (ir+hr
// is a plain sum). Gate math entirely in MFMA C-layout registers. Biases in
// LDS. x-staging: 16 threads/seq x 16 elems (full 256-elem row).
// ============================================================================
__global__ __launch_bounds__(256, 1)
void gru_k(const _Float16* __restrict__ x16,
           const _Float16* __restrict__ wihf, const _Float16* __restrict__ whhf,
           const _Float16* __restrict__ wihb, const _Float16* __restrict__ whhb,
           const float* __restrict__ bihf, const float* __restrict__ bhhf,
           const float* __restrict__ bihb, const float* __restrict__ bhhb,
           const float* __restrict__ h0, const int* __restrict__ counts,
           float* __restrict__ out) {
  __shared__ _Float16 sH[16 * 264];
  __shared__ _Float16 sX[16 * 264];
  __shared__ float sB[1024];          // [0]=bih+bhh(r), [256]=..(z), [512]=bih_n, [768]=bhh_n
  const int blk = blockIdx.x, dir = blk >> 5, g0 = (blk & 31) << 4;
  const _Float16* Wih = dir ? wihb : wihf;
  const _Float16* Whh = dir ? whhb : whhf;
  const float* bih = dir ? bihb : bihf;
  const float* bhh = dir ? bhhb : bhhf;
  const int tid = threadIdx.x, lane = tid & 63, wave = tid >> 6;   // wave 0..3
  const int ar = lane & 15, kq = (lane >> 4) * 8;
  const int ccol = lane & 15, quad = lane >> 4;

  for (int i = tid; i < 256; i += 256) {
    sB[i] = bih[i] + bhh[i];
    sB[256 + i] = bih[256 + i] + bhh[256 + i];
    sB[512 + i] = bih[512 + i];
    sB[768 + i] = bhh[512 + i];
  }

  // ---- register-resident Whh fragments (B-operand layout) ----
  // ntile i = g*4+u: gate g in {r,z,n}, dim sub-tile u; rows g*256+wave*64+u*16
  half8 wh[12][8];
#pragma unroll
  for (int g = 0; g < 3; ++g)
#pragma unroll
    for (int u = 0; u < 4; ++u) {
      const long row = (long)(g * 256 + wave * 64 + u * 16 + ar);
#pragma unroll
      for (int kt = 0; kt < 8; ++kt)
        wh[g * 4 + u][kt] = *(const half8*)(Whh + row * 256 + kt * 32 + kq);
    }
  // streamed Wih row base pointers per (gate, u)
  const _Float16* pWi[3][4];
#pragma unroll
  for (int g = 0; g < 3; ++g)
#pragma unroll
    for (int u = 0; u < 4; ++u)
      pWi[g][u] = Wih + (long)(g * 256 + wave * 64 + u * 16 + ar) * 256 + kq;

  int cn[4];
  float hs[4][4], oa[4][4];
#pragma unroll
  for (int r = 0; r < 4; ++r) cn[r] = counts[g0 + quad * 4 + r];
#pragma unroll
  for (int u = 0; u < 4; ++u)
#pragma unroll
    for (int r = 0; r < 4; ++r) {
      int s = quad * 4 + r, j = wave * 64 + u * 16 + ccol;
      float v = h0[(long)(g0 + s) * 256 + j];
      hs[u][r] = v;
      oa[u][r] = 0.f;
      sH[s * 264 + j] = (_Float16)v;
    }
  // x staging: thread owns (seq tid>>4, 16 elems at (tid&15)*16) — full row
  const int xs = tid >> 4, xo = (tid & 15) * 16;
  const _Float16* xrow = x16 + ((long)(g0 + xs) * 200) * 256 + xo;
  {
    const _Float16* s0 = xrow + (long)(dir ? 199 : 0) * 256;
    *(half8*)(sX + xs * 264 + xo) = *(const half8*)(s0);
    *(half8*)(sX + xs * 264 + xo + 8) = *(const half8*)(s0 + 8);
  }
  __syncthreads();

  for (int step = 0; step < 200; ++step) {
    const int t = dir ? (199 - step) : step;
    int tn = dir ? (t - 1) : (t + 1);
    tn = (tn < 0) ? 0 : (tn > 199 ? 199 : tn);
    const _Float16* xsrc = xrow + (long)tn * 256;
    half8 xr0 = *(const half8*)(xsrc);          // prefetch next x
    half8 xr1 = *(const half8*)(xsrc + 8);
    f32x4 arz[8], ahn[4], axn[4];
#pragma unroll
    for (int i = 0; i < 8; ++i) arz[i] = (f32x4){0.f, 0.f, 0.f, 0.f};
#pragma unroll
    for (int i = 0; i < 4; ++i) {
      ahn[i] = (f32x4){0.f, 0.f, 0.f, 0.f};
      axn[i] = (f32x4){0.f, 0.f, 0.f, 0.f};
    }
#pragma unroll
    for (int kt = 0; kt < 8; ++kt) {
      half8 ah = *(const half8*)(sH + ar * 264 + kt * 32 + kq);
      half8 ax = *(const half8*)(sX + ar * 264 + kt * 32 + kq);
#pragma unroll
      for (int u = 0; u < 4; ++u) {
        half8 wir = *(const half8*)(pWi[0][u] + kt * 32);
        half8 wiz = *(const half8*)(pWi[1][u] + kt * 32);
        half8 win = *(const half8*)(pWi[2][u] + kt * 32);
        arz[u]     = __builtin_amdgcn_mfma_f32_16x16x32_f16(ah, wh[u][kt],     arz[u],     0, 0, 0);
        arz[u]     = __builtin_amdgcn_mfma_f32_16x16x32_f16(ax, wir,           arz[u],     0, 0, 0);
        arz[4 + u] = __builtin_amdgcn_mfma_f32_16x16x32_f16(ah, wh[4 + u][kt], arz[4 + u], 0, 0, 0);
        arz[4 + u] = __builtin_amdgcn_mfma_f32_16x16x32_f16(ax, wiz,           arz[4 + u], 0, 0, 0);
        ahn[u]     = __builtin_amdgcn_mfma_f32_16x16x32_f16(ah, wh[8 + u][kt], ahn[u],     0, 0, 0);
        axn[u]     = __builtin_amdgcn_mfma_f32_16x16x32_f16(ax, win,           axn[u],     0, 0, 0);
      }
    }
    __syncthreads();   // all sH/sX reads done before the updates below
    *(half8*)(sX + xs * 264 + xo) = xr0;         // stage next step's x
    *(half8*)(sX + xs * 264 + xo + 8) = xr1;
#pragma unroll
    for (int u = 0; u < 4; ++u) {
      const int j = wave * 64 + u * 16 + ccol;
      const float brz = sB[j];
      const float bzz = sB[256 + j];
      const float bin_ = sB[512 + j];
      const float bhn_ = sB[768 + j];
#pragma unroll
      for (int r = 0; r < 4; ++r) {
        float pr = arz[u][r] + brz;
        float pz = arz[4 + u][r] + bzz;
        float hn = ahn[u][r] + bhn_;
        float xn = axn[u][r] + bin_;
        float rr = 1.f / (1.f + __expf(-pr));
        float zz = 1.f / (1.f + __expf(-pz));
        float e2 = __expf(2.f * (xn + rr * hn));
        float nn = 1.f - 2.f / (e2 + 1.f);       // tanh
        float h2 = (1.f - zz) * nn + zz * hs[u][r];
        hs[u][r] = h2;
        if (t < cn[r]) oa[u][r] += h2;
        sH[(quad * 4 + r) * 264 + j] = (_Float16)h2;
      }
    }
    __syncthreads();   // h/x updates visible for next step's reads
  }
#pragma unroll
  for (int u = 0; u < 4; ++u)
#pragma unroll
    for (int r = 0; r < 4; ++r) {
      int j = wave * 64 + u * 16 + ccol;
      out[(long)(g0 + quad * 4 + r) * 512 + dir * 256 + j] = oa[u][r] / (float)cn[r];
    }
}

// ============================================================================
// launch
// ============================================================================
extern "C" void kernel_launch(void* const* d_in, const int* in_sizes, int n_in,
                              void* d_out, int out_size, void* d_ws, size_t ws_size,
                              hipStream_t stream) {
  (void)in_sizes; (void)n_in; (void)out_size; (void)ws_size;
  const float* atom_msg  = (const float*)d_in[0];
  const float* pharm_msg = (const float*)d_in[1];
  const float* hyper_msg = (const float*)d_in[2];
  const int* a_cnt = (const int*)d_in[3];
  const int* p_cnt = (const int*)d_in[4];
  const int* h_cnt = (const int*)d_in[5];

  char* ws = (char*)d_ws;
  int* sa = (int*)(ws + O_SA);
  int* sp = (int*)(ws + O_SP);
  int* sh = (int*)(ws + O_SH);
  _Float16* wh = (_Float16*)(ws + O_WH);
  float* h0f = (float*)(ws + O_H0);
  _Float16* Q1 = (_Float16*)(ws + O_Q1);
  _Float16* K1 = (_Float16*)(ws + O_K1);
  _Float16* V1 = (_Float16*)(ws + O_V1);
  _Float16* Q2 = (_Float16*)(ws + O_Q2);
  _Float16* P2 = (_Float16*)(ws + O_P2);
  _Float16* K2 = (_Float16*)(ws + O_K2);
  _Float16* V2 = (_Float16*)(ws + O_V2);
  _Float16* H16 = (_Float16*)(ws + O_H16);

  prefix_k<<<1, 512, 0, stream>>>(a_cnt, p_cnt, h_cnt, sa, sp, sh);
  wconv_k<<<5120, 256, 0, stream>>>(
      (const float*)d_in[6], (const float*)d_in[8], (const float*)d_in[10], (const float*)d_in[12],
      (const float*)d_in[14], (const float*)d_in[16], (const float*)d_in[18], (const float*)d_in[20],
      (const float*)d_in[22], (const float*)d_in[23], (const float*)d_in[26], (const float*)d_in[27],
      wh);

  // ---- MHA1: pharm queries (40) over hyper keys/values (80) ----
  gemm_bt<GF_BIAS | GF_GATHER><<<dim3(2, 160), 256, 0, stream>>>(nullptr, wh + W_P2H_WQ,
      (const float*)d_in[7], Q1, pharm_msg, p_cnt, sp, 40, 256);
  gemm_bt<GF_BIAS | GF_GATHER><<<dim3(2, 320), 256, 0, stream>>>(nullptr, wh + W_P2H_WK,
      (const float*)d_in[9], K1, hyper_msg, h_cnt, sh, 80, 256);
  gemm_bt<GF_BIAS | GF_GATHER><<<dim3(2, 320), 256, 0, stream>>>(nullptr, wh + W_P2H_WV,
      (const float*)d_in[11], V1, hyper_msg, h_cnt, sh, 80, 256);
  mha_k<40, 80, 80, 96, 48, 100, 104><<<dim3(4, NGRAPH), 256, 0, stream>>>(
      Q1, K1, V1, Q1, p_cnt, h_cnt);                       // in-place
  gemm_bt<GF_BIAS | GF_RES><<<dim3(2, 160), 256, 0, stream>>>(Q1, wh + W_P2H_WO,
      (const float*)d_in[13], P2, pharm_msg, p_cnt, sp, 40, 256);

  // ---- MHA2: atom queries (200) over updated pharm keys/values (40) ----
  gemm_bt<GF_BIAS><<<dim3(2, 160), 256, 0, stream>>>(P2, wh + W_A2P_WK,
      (const float*)d_in[17], K2, nullptr, nullptr, nullptr, 1, 256);
  gemm_bt<GF_BIAS><<<dim3(2, 160), 256, 0, stream>>>(P2, wh + W_A2P_WV,
      (const float*)d_in[19], V2, nullptr, nullptr, nullptr, 1, 256);
  gemm_bt<GF_BIAS | GF_GATHER><<<dim3(2, 800), 256, 0, stream>>>(nullptr, wh + W_A2P_WQ,
      (const float*)d_in[15], Q2, atom_msg, a_cnt, sa, 200, 256);
  mha_k<200, 40, 48, 64, 112, 68, 72><<<dim3(4, NGRAPH), 256, 0, stream>>>(
      Q2, K2, V2, Q2, a_cnt, p_cnt);                       // in-place
  gemm_bt<GF_BIAS | GF_RES><<<dim3(2, 800), 256, 0, stream>>>(Q2, wh + W_A2P_WO,
      (const float*)d_in[21], H16, atom_msg, a_cnt, sa, 200, 256);

  // ---- GRU ----
  maxpool_k<<<NGRAPH, 256, 0, stream>>>(H16, h0f);
  gru_k<<<64, 256, 0, stream>>>(H16,
      wh + W_WIH_F, wh + W_WHH_F, wh + W_WIH_B, wh + W_WHH_B,
      (const float*)d_in[24], (const float*)d_in[25],
      (const float*)d_in[28], (const float*)d_in[29],
      h0f, a_cnt, (float*)d_out);
}

// Round 7
// 1910.853 us; speedup vs baseline: 1.9453x; 1.9453x over previous
//
#include <hip/hip_runtime.h>

// ============================================================================
// Hyper_GRU pipeline on MI355X (gfx950), round 6.
// vs round 5 (passed 3717 us, gru_k 3170 us, VGPR=256 — Whh residency refused
// twice): GRU restructured to make residency feasible:
//  - gi = x@Wih^T precomputed by windowed GEMMs (8 windows x 25 steps, both
//    dirs in one launch) into a 39 MB slab aliasing the dead Q1/K1/V1 region
//  - gru_k2 processes one 25-step window per launch; hs/oa state in ws (f32)
//  - GRU loop now holds ONLY: Whh-resident frags (384) + 12 accs (48) + gi
//    prefetch (24) + state (32)  ->  ~490 VGPR, under the 512 cap
//  - amdgpu_waves_per_eu(1,1) pins the allocator target to 1 wave/EU
// ============================================================================

typedef float f32x4 __attribute__((ext_vector_type(4)));
typedef _Float16 half8 __attribute__((ext_vector_type(8)));

#define NGRAPH 512
#define T_CH 25
#define NWIN 8
#define GI_DIR_STRIDE (512L * T_CH * 768)

// ---- workspace arena (bytes); peak 109,051,904 ------------------------------
#define O_SA 0L
#define O_SP 2048L
#define O_SH 4096L
#define O_WH 8192L             // f16 weights: 1,310,720 elems -> ends 2,629,632
#define O_H0 2629632L          // 512*256 f32 -> 3,153,920
#define O_Q1 4194304L          // attention scratch (dead before GRU)
#define O_K1 14680064L
#define O_V1 35651584L
#define O_Q2 4194304L
#define O_P2 56623104L
#define O_K2 67108864L
#define O_V2 77594624L
#define O_H16 56623104L        // 52,428,800 -> 109,051,904 aliases P2,K2,V2 (dead)
#define O_GI 4194304L          // 39,321,600 -> 43,515,904 aliases Q1/K1/V1 (dead)
#define O_ST 43515904L         // 2,097,152  -> 45,613,056 (gru hs/oa state)

// weight element offsets inside WH arena
#define W_P2H_WQ 0
#define W_P2H_WK 65536
#define W_P2H_WV 131072
#define W_P2H_WO 196608
#define W_A2P_WQ 262144
#define W_A2P_WK 327680
#define W_A2P_WV 393216
#define W_A2P_WO 458752
#define W_WIH_F 524288
#define W_WHH_F 720896
#define W_WIH_B 917504
#define W_WHH_B 1114112

// ============================================================================
// small kernels
// ============================================================================

__global__ void prefix_k(const int* __restrict__ ca, const int* __restrict__ cp,
                         const int* __restrict__ chh,
                         int* __restrict__ sa, int* __restrict__ sp, int* __restrict__ sh) {
  __shared__ int buf[512];
  int tid = threadIdx.x;
  for (int m = 0; m < 3; ++m) {
    const int* src = (m == 0) ? ca : (m == 1) ? cp : chh;
    int* dst = (m == 0) ? sa : (m == 1) ? sp : sh;
    int v = src[tid];
    buf[tid] = v;
    __syncthreads();
    for (int off = 1; off < 512; off <<= 1) {
      int add = (tid >= off) ? buf[tid - off] : 0;
      __syncthreads();
      buf[tid] += add;
      __syncthreads();
    }
    dst[tid] = buf[tid] - v;   // exclusive
    __syncthreads();
  }
}

__global__ void wconv_k(const float* s0, const float* s1, const float* s2, const float* s3,
                        const float* s4, const float* s5, const float* s6, const float* s7,
                        const float* s8, const float* s9, const float* s10, const float* s11,
                        _Float16* __restrict__ dst) {
  long i = (long)blockIdx.x * 256 + threadIdx.x;   // grid covers exactly 1,310,720
  const float* s;
  long off;
  if (i < 524288) {
    int m = (int)(i >> 16);
    off = i & 65535;
    s = (m == 0) ? s0 : (m == 1) ? s1 : (m == 2) ? s2 : (m == 3) ? s3
      : (m == 4) ? s4 : (m == 5) ? s5 : (m == 6) ? s6 : s7;
  } else {
    long r = i - 524288;
    int m = (int)(r / 196608);
    off = r - (long)m * 196608;
    s = (m == 0) ? s8 : (m == 1) ? s9 : (m == 2) ? s10 : s11;
  }
  dst[i] = (_Float16)s[off];
}

// h0[b][j] = max_t h[b][t][j]  (all 200 rows incl. padded — matches ref)
__global__ void maxpool_k(const _Float16* __restrict__ h, float* __restrict__ h0) {
  int b = blockIdx.x, j = threadIdx.x;
  float m = -1e30f;
  for (int t = 0; t < 200; ++t) m = fmaxf(m, (float)h[((long)b * 200 + t) * 256 + j]);
  h0[b * 256 + j] = m;
}

// ============================================================================
// GEMM: C[M,N] = A[M,256] @ W[N,256]^T (+bias) (+gathered residual), f16 out.
// GF_GATHER: A rows come from ragged f32 msg (pad/convert fused into staging).
// 128x128 tile, BK=32, 4 waves (2x2), 4x4 16x16x32 MFMAs per wave. M,N %128==0.
// ============================================================================
#define GF_BIAS 1
#define GF_RES  2
#define GF_GATHER 4

template <int FLAGS>
__global__ __launch_bounds__(256, 2)
void gemm_bt(const _Float16* __restrict__ A, const _Float16* __restrict__ W,
             const float* __restrict__ bias, _Float16* __restrict__ Ch,
             const float* __restrict__ rmsg, const int* __restrict__ rcnt,
             const int* __restrict__ rstart, int rmaxn, int N) {
  __shared__ _Float16 sA[128 * 40];   // rows padded 32->40
  __shared__ _Float16 sB[128 * 40];
  const int tid = threadIdx.x;
  const int lane = tid & 63, wave = tid >> 6;
  const int wr = wave >> 1, wc = wave & 1;
  const long bm0 = (long)blockIdx.y * 128;
  const long bn0 = (long)blockIdx.x * 128;
  const int r0 = tid >> 2, c0 = tid & 3;            // thread stages rows r0, r0+64
  const _Float16* gB = W + (bn0 + r0) * 256 + c0 * 8;

  const _Float16* gA0 = nullptr;
  const _Float16* gA1 = nullptr;
  const float* gs0 = nullptr;
  const float* gs1 = nullptr;
  bool v0 = false, v1 = false;
  if (FLAGS & GF_GATHER) {
    int row0 = (int)bm0 + r0, row1 = row0 + 64;
    int b0 = row0 / rmaxn, p0 = row0 - b0 * rmaxn;
    int b1 = row1 / rmaxn, p1 = row1 - b1 * rmaxn;
    v0 = p0 < rcnt[b0];
    v1 = p1 < rcnt[b1];
    gs0 = rmsg + (long)(rstart[b0] + p0) * 256 + c0 * 8;
    gs1 = rmsg + (long)(rstart[b1] + p1) * 256 + c0 * 8;
  } else {
    gA0 = A + (bm0 + r0) * 256 + c0 * 8;
    gA1 = gA0 + 64 * 256;
  }
  auto loadA = [&](int kt, bool hi) -> half8 {
    if (FLAGS & GF_GATHER) {
      half8 h = {};
      const float* g = hi ? gs1 : gs0;
      if (hi ? v1 : v0) {
        float4 f0 = *(const float4*)(g + kt * 32);
        float4 f1 = *(const float4*)(g + kt * 32 + 4);
        h[0] = (_Float16)f0.x; h[1] = (_Float16)f0.y;
        h[2] = (_Float16)f0.z; h[3] = (_Float16)f0.w;
        h[4] = (_Float16)f1.x; h[5] = (_Float16)f1.y;
        h[6] = (_Float16)f1.z; h[7] = (_Float16)f1.w;
      }
      return h;
    } else {
      return hi ? *(const half8*)(gA1 + kt * 32) : *(const half8*)(gA0 + kt * 32);
    }
  };

  f32x4 acc[4][4] = {};
  half8 ra0 = loadA(0, false);
  half8 ra1 = loadA(0, true);
  half8 rb0 = *(const half8*)(gB);
  half8 rb1 = *(const half8*)(gB + 64 * 256);
  const int ar = lane & 15, kq = (lane >> 4) * 8;
  for (int kt = 0; kt < 8; ++kt) {
    __syncthreads();
    *(half8*)(sA + r0 * 40 + c0 * 8) = ra0;
    *(half8*)(sA + (r0 + 64) * 40 + c0 * 8) = ra1;
    *(half8*)(sB + r0 * 40 + c0 * 8) = rb0;
    *(half8*)(sB + (r0 + 64) * 40 + c0 * 8) = rb1;
    __syncthreads();
    if (kt < 7) {
      ra0 = loadA(kt + 1, false);
      ra1 = loadA(kt + 1, true);
      rb0 = *(const half8*)(gB + (kt + 1) * 32);
      rb1 = *(const half8*)(gB + 64 * 256 + (kt + 1) * 32);
    }
    half8 af[4], bf[4];
#pragma unroll
    for (int mt = 0; mt < 4; ++mt)
      af[mt] = *(const half8*)(sA + (wr * 64 + mt * 16 + ar) * 40 + kq);
#pragma unroll
    for (int nt = 0; nt < 4; ++nt)
      bf[nt] = *(const half8*)(sB + (wc * 64 + nt * 16 + ar) * 40 + kq);
#pragma unroll
    for (int mt = 0; mt < 4; ++mt)
#pragma unroll
      for (int nt = 0; nt < 4; ++nt)
        acc[mt][nt] = __builtin_amdgcn_mfma_f32_16x16x32_f16(af[mt], bf[nt], acc[mt][nt], 0, 0, 0);
  }
  // epilogue: C/D layout col=lane&15, row=(lane>>4)*4+reg (m89-verified)
  const int cr = (lane >> 4) * 4, cc = lane & 15;
#pragma unroll
  for (int mt = 0; mt < 4; ++mt) {
#pragma unroll
    for (int nt = 0; nt < 4; ++nt) {
      const long col = bn0 + wc * 64 + nt * 16 + cc;
      float bv = (FLAGS & GF_BIAS) ? bias[col] : 0.f;
#pragma unroll
      for (int r = 0; r < 4; ++r) {
        const long row = bm0 + wr * 64 + mt * 16 + cr + r;
        float v = acc[mt][nt][r] + bv;
        if (FLAGS & GF_RES) {     // residual = re-gathered ragged message (f32)
          int bb = (int)(row / rmaxn);
          int p = (int)(row - (long)bb * rmaxn);
          if (p < rcnt[bb]) v += rmsg[(long)(rstart[bb] + p) * 256 + col];
        }
        Ch[row * N + col] = (_Float16)v;
      }
    }
  }
}

// ============================================================================
// gi window GEMM: gi[dir][b][i][0..767] = x[b][t(dir,w,i)] @ Wih_dir^T
// (no bias — biases are folded in gru_k2's LDS). M=512*25=12800, N=768, K=256.
// grid (6, 100, 2): z = direction. t = w*25+i (fwd) / 199-w*25-i (bwd).
// ============================================================================
__global__ __launch_bounds__(256, 2)
void gemm_gi(const _Float16* __restrict__ X,     // H16 [512][200][256]
             const _Float16* __restrict__ wihf, const _Float16* __restrict__ wihb,
             _Float16* __restrict__ gi, int w) {
  __shared__ _Float16 sA[128 * 40];
  __shared__ _Float16 sB[128 * 40];
  const int dir = blockIdx.z;
  const _Float16* W = dir ? wihb : wihf;
  _Float16* Cg = gi + (long)dir * GI_DIR_STRIDE;
  const int tid = threadIdx.x;
  const int lane = tid & 63, wave = tid >> 6;
  const int wr = wave >> 1, wc = wave & 1;
  const long bm0 = (long)blockIdx.y * 128;
  const long bn0 = (long)blockIdx.x * 128;
  const int r0 = tid >> 2, c0 = tid & 3;
  int row0 = (int)bm0 + r0, row1 = row0 + 64;
  int b0 = row0 / T_CH, i0 = row0 - b0 * T_CH;
  int b1 = row1 / T_CH, i1 = row1 - b1 * T_CH;
  int t0 = dir ? (199 - T_CH * w - i0) : (T_CH * w + i0);
  int t1 = dir ? (199 - T_CH * w - i1) : (T_CH * w + i1);
  const _Float16* gA0 = X + ((long)b0 * 200 + t0) * 256 + c0 * 8;
  const _Float16* gA1 = X + ((long)b1 * 200 + t1) * 256 + c0 * 8;
  const _Float16* gB = W + (long)(bn0 + r0) * 256 + c0 * 8;

  f32x4 acc[4][4] = {};
  half8 ra0 = *(const half8*)(gA0);
  half8 ra1 = *(const half8*)(gA1);
  half8 rb0 = *(const half8*)(gB);
  half8 rb1 = *(const half8*)(gB + 64 * 256);
  const int ar = lane & 15, kq = (lane >> 4) * 8;
  for (int kt = 0; kt < 8; ++kt) {
    __syncthreads();
    *(half8*)(sA + r0 * 40 + c0 * 8) = ra0;
    *(half8*)(sA + (r0 + 64) * 40 + c0 * 8) = ra1;
    *(half8*)(sB + r0 * 40 + c0 * 8) = rb0;
    *(half8*)(sB + (r0 + 64) * 40 + c0 * 8) = rb1;
    __syncthreads();
    if (kt < 7) {
      ra0 = *(const half8*)(gA0 + (kt + 1) * 32);
      ra1 = *(const half8*)(gA1 + (kt + 1) * 32);
      rb0 = *(const half8*)(gB + (kt + 1) * 32);
      rb1 = *(const half8*)(gB + 64 * 256 + (kt + 1) * 32);
    }
    half8 af[4], bf[4];
#pragma unroll
    for (int mt = 0; mt < 4; ++mt)
      af[mt] = *(const half8*)(sA + (wr * 64 + mt * 16 + ar) * 40 + kq);
#pragma unroll
    for (int nt = 0; nt < 4; ++nt)
      bf[nt] = *(const half8*)(sB + (wc * 64 + nt * 16 + ar) * 40 + kq);
#pragma unroll
    for (int mt = 0; mt < 4; ++mt)
#pragma unroll
      for (int nt = 0; nt < 4; ++nt)
        acc[mt][nt] = __builtin_amdgcn_mfma_f32_16x16x32_f16(af[mt], bf[nt], acc[mt][nt], 0, 0, 0);
  }
  const int cr = (lane >> 4) * 4, cc = lane & 15;
#pragma unroll
  for (int mt = 0; mt < 4; ++mt)
#pragma unroll
    for (int nt = 0; nt < 4; ++nt) {
      const long col = bn0 + wc * 64 + nt * 16 + cc;
#pragma unroll
      for (int r = 0; r < 4; ++r) {
        const long row = bm0 + wr * 64 + mt * 16 + cr + r;
        Cg[row * 768 + col] = (_Float16)acc[mt][nt][r];
      }
    }
}

// ============================================================================
// GRU window segment. 64 blocks x 256 threads, 1 wave/SIMD (waves_per_eu 1,1
// -> 512-VGPR cap). Block = 16 seqs of one direction; wave w owns gate dims
// [64w,64w+64) of all 3 gates. Whh register-resident (12 ntiles x 8 kfrags =
// 384 VGPR). Per step: 8 ds_read_b128 (sH) + 96 MFMA + 48 scalar gi loads
// (prefetched in 2 halves) + gate math in C-layout regs. hs/oa state carried
// across the 8 window launches in ws (f32).
// ============================================================================
__global__ __launch_bounds__(256) __attribute__((amdgpu_waves_per_eu(1, 1)))
void gru_k2(const _Float16* __restrict__ gi,
            const _Float16* __restrict__ whhf, const _Float16* __restrict__ whhb,
            const float* __restrict__ bihf, const float* __restrict__ bhhf,
            const float* __restrict__ bihb, const float* __restrict__ bhhb,
            const float* __restrict__ h0, const int* __restrict__ counts,
            float* __restrict__ stateS, float* __restrict__ out, int w) {
  __shared__ _Float16 sH[16 * 264];
  __shared__ float sB[1024];   // [0]=bih+bhh r, [256]=bih+bhh z, [512]=bih_n, [768]=bhh_n
  const int blk = blockIdx.x, dir = blk >> 5, g0 = (blk & 31) << 4;
  const _Float16* Whh = dir ? whhb : whhf;
  const float* bih = dir ? bihb : bihf;
  const float* bhh = dir ? bhhb : bhhf;
  const int tid = threadIdx.x, lane = tid & 63, wave = tid >> 6;
  const int ar = lane & 15, kq = (lane >> 4) * 8;
  const int ccol = lane & 15, quad = lane >> 4;

  {
    int i = tid;
    sB[i] = bih[i] + bhh[i];
    sB[256 + i] = bih[256 + i] + bhh[256 + i];
    sB[512 + i] = bih[512 + i];
    sB[768 + i] = bhh[512 + i];
  }

  // register-resident Whh fragments (B-operand layout); ntile g*4+u
  half8 wh[12][8];
#pragma unroll
  for (int g = 0; g < 3; ++g)
#pragma unroll
    for (int u = 0; u < 4; ++u) {
      const long row = (long)(g * 256 + wave * 64 + u * 16 + ar);
#pragma unroll
      for (int kt = 0; kt < 8; ++kt)
        wh[g * 4 + u][kt] = *(const half8*)(Whh + row * 256 + kt * 32 + kq);
    }

  float* st = stateS + ((long)blk * 256 + tid) * 32;
  int cn[4];
  float hs[4][4], oa[4][4];
#pragma unroll
  for (int r = 0; r < 4; ++r) cn[r] = counts[g0 + quad * 4 + r];
  if (w == 0) {
#pragma unroll
    for (int u = 0; u < 4; ++u)
#pragma unroll
      for (int r = 0; r < 4; ++r) {
        hs[u][r] = h0[(long)(g0 + quad * 4 + r) * 256 + wave * 64 + u * 16 + ccol];
        oa[u][r] = 0.f;
      }
  } else {
#pragma unroll
    for (int u = 0; u < 4; ++u)
#pragma unroll
      for (int r = 0; r < 4; ++r) {
        hs[u][r] = st[u * 4 + r];
        oa[u][r] = st[16 + u * 4 + r];
      }
  }
#pragma unroll
  for (int u = 0; u < 4; ++u)
#pragma unroll
    for (int r = 0; r < 4; ++r)
      sH[(quad * 4 + r) * 264 + wave * 64 + u * 16 + ccol] = (_Float16)hs[u][r];
  __syncthreads();

  const _Float16* gid = gi + (long)dir * GI_DIR_STRIDE;

  for (int s = 0; s < T_CH; ++s) {
    const int sg = w * T_CH + s;
    const int t = dir ? (199 - sg) : sg;
    // gi row bases for this step (seq r)
    const _Float16* gp[4];
#pragma unroll
    for (int r = 0; r < 4; ++r)
      gp[r] = gid + ((long)(g0 + quad * 4 + r) * T_CH + s) * 768 + wave * 64 + ccol;
    // prefetch gi for u=0,1 (latency hidden under the MFMA phase)
    float gi01[2][3][4];
#pragma unroll
    for (int u = 0; u < 2; ++u)
#pragma unroll
      for (int g = 0; g < 3; ++g)
#pragma unroll
        for (int r = 0; r < 4; ++r)
          gi01[u][g][r] = (float)gp[r][g * 256 + u * 16];

    f32x4 agh[12];
#pragma unroll
    for (int i = 0; i < 12; ++i) agh[i] = (f32x4){0.f, 0.f, 0.f, 0.f};
#pragma unroll
    for (int kt = 0; kt < 8; ++kt) {
      half8 ah = *(const half8*)(sH + ar * 264 + kt * 32 + kq);
#pragma unroll
      for (int n = 0; n < 12; ++n)
        agh[n] = __builtin_amdgcn_mfma_f32_16x16x32_f16(ah, wh[n][kt], agh[n], 0, 0, 0);
    }
    __syncthreads();   // sH reads done before gate-phase writes
    // prefetch gi for u=2,3 (overlaps gate math of u=0,1)
    float gi23[2][3][4];
#pragma unroll
    for (int u = 0; u < 2; ++u)
#pragma unroll
      for (int g = 0; g < 3; ++g)
#pragma unroll
        for (int r = 0; r < 4; ++r)
          gi23[u][g][r] = (float)gp[r][g * 256 + (2 + u) * 16];

#pragma unroll
    for (int u = 0; u < 4; ++u) {
      const int j = wave * 64 + u * 16 + ccol;
      const float brz = sB[j];
      const float bzz = sB[256 + j];
      const float bin_ = sB[512 + j];
      const float bhn_ = sB[768 + j];
#pragma unroll
      for (int r = 0; r < 4; ++r) {
        float gir = (u < 2) ? gi01[u][0][r] : gi23[u - 2][0][r];
        float giz = (u < 2) ? gi01[u][1][r] : gi23[u - 2][1][r];
        float gin = (u < 2) ? gi01[u][2][r] : gi23[u - 2][2][r];
        float pr = agh[u][r] + gir + brz;
        float pz = agh[4 + u][r] + giz + bzz;
        float hn = agh[8 + u][r] + bhn_;
        float xn = gin + bin_;
        float rr = 1.f / (1.f + __expf(-pr));
        float zz = 1.f / (1.f + __expf(-pz));
        float e2 = __expf(2.f * (xn + rr * hn));
        float nn = 1.f - 2.f / (e2 + 1.f);       // tanh
        float h2 = (1.f - zz) * nn + zz * hs[u][r];
        hs[u][r] = h2;
        if (t < cn[r]) oa[u][r] += h2;
        sH[(quad * 4 + r) * 264 + j] = (_Float16)h2;
      }
    }
    __syncthreads();   // h updates visible for next step
  }

  if (w == NWIN - 1) {
#pragma unroll
    for (int u = 0; u < 4; ++u)
#pragma unroll
      for (int r = 0; r < 4; ++r) {
        int j = wave * 64 + u * 16 + ccol;
        out[(long)(g0 + quad * 4 + r) * 512 + dir * 256 + j] = oa[u][r] / (float)cn[r];
      }
  } else {
#pragma unroll
    for (int u = 0; u < 4; ++u)
#pragma unroll
      for (int r = 0; r < 4; ++r) {
        st[u * 4 + r] = hs[u][r];
        st[16 + u * 4 + r] = oa[u][r];
      }
  }
}

// ============================================================================
// Fused MHA per (head, graph): S = Q K^T/8, masked softmax (uniform over all
// MAXK keys when the query row is padded — matches ref's -1e9 fill), O = P V.
// Og may alias Qg (in-place).
// ============================================================================
template <int MAXQ, int MAXK, int NKP, int KKP, int CH, int SSTR, int VSTR>
__global__ __launch_bounds__(256, 2)
void mha_k(const _Float16* Qg, const _Float16* __restrict__ Kg,
           const _Float16* __restrict__ Vg, _Float16* Og,
           const int* __restrict__ qcnt, const int* __restrict__ kcnt) {
  constexpr int MTOT = (MAXQ + 15) & ~15;
  constexpr int NCH = (MTOT + CH - 1) / CH;
  __shared__ float sS[CH * SSTR];
  __shared__ _Float16 sK[NKP * 72];
  __shared__ _Float16 sV[64 * VSTR];   // V transposed: sV[d][kk]
  const int h = blockIdx.x, b = blockIdx.y;
  const int tid = threadIdx.x, lane = tid & 63, wave = tid >> 6;
  const int qc = qcnt[b], kc = kcnt[b];
  const long qbase = ((long)b * MAXQ) * 256 + h * 64;
  const long kbase = ((long)b * MAXK) * 256 + h * 64;
  const int ar = lane & 15, kq = (lane >> 4) * 8;
  for (int i = tid; i < NKP * 64; i += 256) {
    int k = i >> 6, d = i & 63;
    sK[k * 72 + d] = (k < MAXK) ? Kg[kbase + (long)k * 256 + d] : (_Float16)0.f;
  }
  for (int i = tid; i < KKP * 64; i += 256) {
    int kk = i >> 6, d = i & 63;
    sV[d * VSTR + kk] = (kk < MAXK) ? Vg[kbase + (long)kk * 256 + d] : (_Float16)0.f;
  }
  __syncthreads();
  for (int ch = 0; ch < NCH; ++ch) {
    const int rows = (CH < MTOT - ch * CH) ? CH : (MTOT - ch * CH);
    const int mt_n = rows >> 4, st_n = NKP >> 4;
    // ---- scores ----
    for (int idx = wave; idx < mt_n * st_n; idx += 4) {
      int lmt = idx / st_n, nt = idx - lmt * st_n;
      int q = ch * CH + lmt * 16 + ar;
      int n0 = nt * 16;
      f32x4 acc = {0.f, 0.f, 0.f, 0.f};
#pragma unroll
      for (int ks = 0; ks < 2; ++ks) {
        half8 a = {};
        if (q < MAXQ) a = *(const half8*)(Qg + qbase + (long)q * 256 + ks * 32 + kq);
        half8 bb = *(const half8*)(sK + (n0 + ar) * 72 + ks * 32 + kq);
        acc = __builtin_amdgcn_mfma_f32_16x16x32_f16(a, bb, acc, 0, 0, 0);
      }
      int sr = lmt * 16 + (lane >> 4) * 4, sc = n0 + ar;
#pragma unroll
      for (int r = 0; r < 4; ++r) sS[(sr + r) * SSTR + sc] = acc[r];
    }
    __syncthreads();
    // ---- softmax per row ----
    if (tid < rows) {
      int q = ch * CH + tid;
      float sv[MAXK];
#pragma unroll
      for (int k4 = 0; k4 < MAXK / 4; ++k4) {
        f32x4 v = *(const f32x4*)&sS[tid * SSTR + k4 * 4];
        sv[k4 * 4 + 0] = v[0]; sv[k4 * 4 + 1] = v[1];
        sv[k4 * 4 + 2] = v[2]; sv[k4 * 4 + 3] = v[3];
      }
      if (q < qc) {
        float m = -1e30f;
#pragma unroll
        for (int k = 0; k < MAXK; ++k) if (k < kc) m = fmaxf(m, sv[k]);
        float s = 0.f;
#pragma unroll
        for (int k = 0; k < MAXK; ++k) {
          float e = (k < kc) ? __expf((sv[k] - m) * 0.125f) : 0.f;
          sv[k] = e; s += e;
        }
        float inv = 1.f / s;
#pragma unroll
        for (int k = 0; k < MAXK; ++k) sv[k] *= inv;
      } else {
#pragma unroll
        for (int k = 0; k < MAXK; ++k) sv[k] = 1.f / (float)MAXK;
      }
#pragma unroll
      for (int k4 = 0; k4 < MAXK / 4; ++k4) {
        f32x4 v; v[0] = sv[k4*4+0]; v[1] = sv[k4*4+1]; v[2] = sv[k4*4+2]; v[3] = sv[k4*4+3];
        *(f32x4*)&sS[tid * SSTR + k4 * 4] = v;
      }
      for (int k = MAXK; k < KKP; ++k) sS[tid * SSTR + k] = 0.f;
    }
    __syncthreads();
    // ---- P @ V ----
    for (int idx = wave; idx < mt_n * 4; idx += 4) {
      int lmt = idx >> 2, nt = idx & 3;
      int lm = lmt * 16 + ar;
      f32x4 acc = {0.f, 0.f, 0.f, 0.f};
#pragma unroll
      for (int ks = 0; ks < KKP / 32; ++ks) {
        const float* ps = &sS[lm * SSTR + ks * 32 + kq];
        f32x4 p0 = *(const f32x4*)ps;
        f32x4 p1 = *(const f32x4*)(ps + 4);
        half8 a;
        a[0] = (_Float16)p0[0]; a[1] = (_Float16)p0[1]; a[2] = (_Float16)p0[2]; a[3] = (_Float16)p0[3];
        a[4] = (_Float16)p1[0]; a[5] = (_Float16)p1[1]; a[6] = (_Float16)p1[2]; a[7] = (_Float16)p1[3];
        half8 bb = *(const half8*)(sV + (nt * 16 + ar) * VSTR + ks * 32 + kq);
        acc = __builtin_amdgcn_mfma_f32_16x16x32_f16(a, bb, acc, 0, 0, 0);
      }
      int q0 = ch * CH + lmt * 16 + (lane >> 4) * 4;
      int dcol = nt * 16 + ar;
#pragma unroll
      for (int r = 0; r < 4; ++r) {
        int q = q0 + r;
        if (q < MAXQ) Og[qbase + (long)q * 256 + dcol] = (_Float16)acc[r];
      }
    }
    __syncthreads();
  }
}

// ============================================================================
// launch
// ============================================================================
extern "C" void kernel_launch(void* const* d_in, const int* in_sizes, int n_in,
                              void* d_out, int out_size, void* d_ws, size_t ws_size,
                              hipStream_t stream) {
  (void)in_sizes; (void)n_in; (void)out_size; (void)ws_size;
  const float* atom_msg  = (const float*)d_in[0];
  const float* pharm_msg = (const float*)d_in[1];
  const float* hyper_msg = (const float*)d_in[2];
  const int* a_cnt = (const int*)d_in[3];
  const int* p_cnt = (const int*)d_in[4];
  const int* h_cnt = (const int*)d_in[5];

  char* ws = (char*)d_ws;
  int* sa = (int*)(ws + O_SA);
  int* sp = (int*)(ws + O_SP);
  int* sh = (int*)(ws + O_SH);
  _Float16* wh = (_Float16*)(ws + O_WH);
  float* h0f = (float*)(ws + O_H0);
  _Float16* Q1 = (_Float16*)(ws + O_Q1);
  _Float16* K1 = (_Float16*)(ws + O_K1);
  _Float16* V1 = (_Float16*)(ws + O_V1);
  _Float16* Q2 = (_Float16*)(ws + O_Q2);
  _Float16* P2 = (_Float16*)(ws + O_P2);
  _Float16* K2 = (_Float16*)(ws + O_K2);
  _Float16* V2 = (_Float16*)(ws + O_V2);
  _Float16* H16 = (_Float16*)(ws + O_H16);
  _Float16* GI  = (_Float16*)(ws + O_GI);
  float* ST = (float*)(ws + O_ST);

  prefix_k<<<1, 512, 0, stream>>>(a_cnt, p_cnt, h_cnt, sa, sp, sh);
  wconv_k<<<5120, 256, 0, stream>>>(
      (const float*)d_in[6], (const float*)d_in[8], (const float*)d_in[10], (const float*)d_in[12],
      (const float*)d_in[14], (const float*)d_in[16], (const float*)d_in[18], (const float*)d_in[20],
      (const float*)d_in[22], (const float*)d_in[23], (const float*)d_in[26], (const float*)d_in[27],
      wh);

  // ---- MHA1: pharm queries (40) over hyper keys/values (80) ----
  gemm_bt<GF_BIAS | GF_GATHER><<<dim3(2, 160), 256, 0, stream>>>(nullptr, wh + W_P2H_WQ,
      (const float*)d_in[7], Q1, pharm_msg, p_cnt, sp, 40, 256);
  gemm_bt<GF_BIAS | GF_GATHER><<<dim3(2, 320), 256, 0, stream>>>(nullptr, wh + W_P2H_WK,
      (const float*)d_in[9], K1, hyper_msg, h_cnt, sh, 80, 256);
  gemm_bt<GF_BIAS | GF_GATHER><<<dim3(2, 320), 256, 0, stream>>>(nullptr, wh + W_P2H_WV,
      (const float*)d_in[11], V1, hyper_msg, h_cnt, sh, 80, 256);
  mha_k<40, 80, 80, 96, 48, 100, 104><<<dim3(4, NGRAPH), 256, 0, stream>>>(
      Q1, K1, V1, Q1, p_cnt, h_cnt);                       // in-place
  gemm_bt<GF_BIAS | GF_RES><<<dim3(2, 160), 256, 0, stream>>>(Q1, wh + W_P2H_WO,
      (const float*)d_in[13], P2, pharm_msg, p_cnt, sp, 40, 256);

  // ---- MHA2: atom queries (200) over updated pharm keys/values (40) ----
  gemm_bt<GF_BIAS><<<dim3(2, 160), 256, 0, stream>>>(P2, wh + W_A2P_WK,
      (const float*)d_in[17], K2, nullptr, nullptr, nullptr, 1, 256);
  gemm_bt<GF_BIAS><<<dim3(2, 160), 256, 0, stream>>>(P2, wh + W_A2P_WV,
      (const float*)d_in[19], V2, nullptr, nullptr, nullptr, 1, 256);
  gemm_bt<GF_BIAS | GF_GATHER><<<dim3(2, 800), 256, 0, stream>>>(nullptr, wh + W_A2P_WQ,
      (const float*)d_in[15], Q2, atom_msg, a_cnt, sa, 200, 256);
  mha_k<200, 40, 48, 64, 112, 68, 72><<<dim3(4, NGRAPH), 256, 0, stream>>>(
      Q2, K2, V2, Q2, a_cnt, p_cnt);                       // in-place
  gemm_bt<GF_BIAS | GF_RES><<<dim3(2, 800), 256, 0, stream>>>(Q2, wh + W_A2P_WO,
      (const float*)d_in[21], H16, atom_msg, a_cnt, sa, 200, 256);

  // ---- GRU: h0 maxpool, then 8 windows of (gi GEMM -> 25-step segment) ----
  maxpool_k<<<NGRAPH, 256, 0, stream>>>(H16, h0f);
  for (int w = 0; w < NWIN; ++w) {
    gemm_gi<<<dim3(6, 100, 2), 256, 0, stream>>>(H16, wh + W_WIH_F, wh + W_WIH_B, GI, w);
    gru_k2<<<64, 256, 0, stream>>>(GI, wh + W_WHH_F, wh + W_WHH_B,
        (const float*)d_in[24], (const float*)d_in[25],
        (const float*)d_in[28], (const float*)d_in[29],
        h0f, a_cnt, ST, (float*)d_out, w);
  }
}